// Round 4
// baseline (3273.481 us; speedup 1.0000x reference)
//
#include <hip/hip_runtime.h>
#include <stdint.h>

// GGSNN: B=4096 graphs, N=64 nodes, D=128. One workgroup per graph; all 4
// propagation steps run in-LDS. bf16 MFMA with hi/lo split activations AND
// hi/lo split weights (3-term products -> ~f32 accuracy).
// Wave mapping: 8 waves, each owns all 64 rows x 16 output cols (min weight traffic).
// 128-wide LDS buffers: stride 128 + XOR-16B-slot swizzle (conflict-free, T2-style).

typedef __attribute__((ext_vector_type(8))) short bf16x8;
typedef __attribute__((ext_vector_type(4))) float f32x4;

#define TSTRIDE 72   // stride for 64-wide buffers (M rows, T rows); 2-way banks = free

__device__ __forceinline__ uint16_t f2b(float x){           // f32 -> bf16 RNE
    uint32_t u = __float_as_uint(x);
    u += 0x7FFFu + ((u >> 16) & 1u);
    return (uint16_t)(u >> 16);
}
__device__ __forceinline__ float b2f(uint16_t h){ return __uint_as_float(((uint32_t)h) << 16); }
__device__ __forceinline__ float sigm(float x){ return 1.0f/(1.0f + __expf(-x)); }
__device__ __forceinline__ float tanhfast(float x){ float e = __expf(2.0f*x); return 1.0f - 2.0f/(e+1.0f); }

// swizzled flat index into a [64][128] bf16 LDS buffer: XOR the 16B slot with row&7
__device__ __forceinline__ int SW(int row, int col){
    return row*128 + ((((col>>3) ^ (row&7)))<<3) + (col&7);
}
__device__ __forceinline__ bf16x8 frag128(const uint16_t* buf, int row, int kb, int g){
    int slot = (kb*4 + g) ^ (row & 7);
    return *(const bf16x8*)&buf[row*128 + slot*8];
}
__device__ __forceinline__ bf16x8 frag64(const uint16_t* buf, int row, int kb, int g){
    return *(const bf16x8*)&buf[row*TSTRIDE + kb*32 + g*8];
}
__device__ __forceinline__ void st8(uint16_t* p, const uint16_t v[8]){
    uint4 q;
    q.x = (uint32_t)v[0] | ((uint32_t)v[1]<<16);
    q.y = (uint32_t)v[2] | ((uint32_t)v[3]<<16);
    q.z = (uint32_t)v[4] | ((uint32_t)v[5]<<16);
    q.w = (uint32_t)v[6] | ((uint32_t)v[7]<<16);
    *(uint4*)p = q;
}

// ---- weight/bias prep. ws layout:
//   whi[7*16384] bf16, wlo[7*16384] bf16 : 0=Wp 1=Wz 2=Wr 3=Wh 4=Uz 5=Ur 6=Uh ([out][in])
//   bias[512] f32: [0,128)=64*Wp_b  [128)=Wz_b+Uz_b  [256)=Wr_b+Ur_b  [384)=Wh_b+Uh_b
__global__ void prep_weights(const float* __restrict__ Wp, const float* __restrict__ Wz,
                             const float* __restrict__ Wr, const float* __restrict__ Wh,
                             const float* __restrict__ Uz, const float* __restrict__ Ur,
                             const float* __restrict__ Uh,
                             const float* __restrict__ Wp_b,
                             const float* __restrict__ Wz_b, const float* __restrict__ Uz_b,
                             const float* __restrict__ Wr_b, const float* __restrict__ Ur_b,
                             const float* __restrict__ Wh_b, const float* __restrict__ Uh_b,
                             uint16_t* __restrict__ whi, uint16_t* __restrict__ wlo,
                             float* __restrict__ bias)
{
    int idx = blockIdx.x * 256 + threadIdx.x;
    if (idx < 7*16384){
        int w = idx >> 14, off = idx & 16383;
        const float* s;
        switch(w){
            case 0: s = Wp; break;  case 1: s = Wz; break;
            case 2: s = Wr; break;  case 3: s = Wh; break;
            case 4: s = Uz; break;  case 5: s = Ur; break;
            default: s = Uh; break;
        }
        float v = s[off];
        uint16_t h = f2b(v);
        whi[idx] = h;
        wlo[idx] = f2b(v - b2f(h));
    }
    if (idx < 128){
        bias[idx]       = 64.0f * Wp_b[idx];      // N * Wp_b (bias summed over nodes)
        bias[128+idx]   = Wz_b[idx] + Uz_b[idx];
        bias[256+idx]   = Wr_b[idx] + Ur_b[idx];
        bias[384+idx]   = Wh_b[idx] + Uh_b[idx];
    }
}

#define MFMA(a,b,c) __builtin_amdgcn_mfma_f32_16x16x32_bf16((a),(b),(c),0,0,0)
// weight B-fragment: rows C0..C0+15 of matrix `mat` (row-major [out=128][in=128])
#define WFRAG(arr, mat, kb) (*(const bf16x8*)&(arr)[(mat)*16384 + (C0 + r16)*128 + (kb)*32 + g*8])

__global__ __launch_bounds__(512, 2) void ggsnn(const float* __restrict__ h0,
                                                const float* __restrict__ mask,
                                                const uint16_t* __restrict__ whi,
                                                const uint16_t* __restrict__ wlo,
                                                const float* __restrict__ bias,
                                                float* __restrict__ out)
{
    __shared__ uint16_t Mhi[64*TSTRIDE], Mlo[64*TSTRIDE];   // mask (64-wide rows)
    __shared__ uint16_t Thi[128*TSTRIDE], Tlo[128*TSTRIDE]; // h^T (rows=feature, 64-wide)
    __shared__ uint16_t Hhi[64*128], Hlo[64*128];           // h       (swizzled)
    __shared__ uint16_t Ahi[64*128], Alo[64*128];           // agg / u (swizzled)
    __shared__ uint16_t Nhi[64*128], Nlo[64*128];           // neigh   (swizzled)
    __shared__ float sbias[512];

    const int tid  = threadIdx.x;
    const int lane = tid & 63;
    const int g    = lane >> 4;      // 0..3  (k-group / D-row-subgroup)
    const int r16  = lane & 15;
    const int wid  = tid >> 6;       // 8 waves
    const int C0   = wid * 16;       // each wave owns output cols [C0, C0+16)
    const int b    = blockIdx.x;

    // ---- setup: mask -> Mhi/Mlo
    {
        const float* mb = mask + (size_t)b*4096;
        int e0 = tid*8;                       // 8 floats/thread
        int row = e0 >> 6, col = e0 & 63;
        float4 v0 = *(const float4*)(mb + e0);
        float4 v1 = *(const float4*)(mb + e0 + 4);
        float v[8] = {v0.x,v0.y,v0.z,v0.w,v1.x,v1.y,v1.z,v1.w};
        uint16_t hi[8], lo[8];
        #pragma unroll
        for (int j=0;j<8;j++){ hi[j]=f2b(v[j]); lo[j]=f2b(v[j]-b2f(hi[j])); }
        st8(&Mhi[row*TSTRIDE+col], hi);
        st8(&Mlo[row*TSTRIDE+col], lo);
    }
    // ---- setup: h0 -> Hhi/Hlo (swizzled) + transposed Thi/Tlo
    {
        const float* hb = h0 + (size_t)b*8192;
        int row = tid >> 3;                   // 16 floats/thread
        int col = (tid & 7) * 16;
        float v[16];
        #pragma unroll
        for (int j=0;j<16;j+=4){ float4 t = *(const float4*)(hb + row*128 + col + j); v[j]=t.x; v[j+1]=t.y; v[j+2]=t.z; v[j+3]=t.w; }
        uint16_t hi[16], lo[16];
        #pragma unroll
        for (int j=0;j<16;j++){ hi[j]=f2b(v[j]); lo[j]=f2b(v[j]-b2f(hi[j])); }
        st8(&Hhi[SW(row,col)],   hi);   st8(&Hhi[SW(row,col+8)],   hi+8);
        st8(&Hlo[SW(row,col)],   lo);   st8(&Hlo[SW(row,col+8)],   lo+8);
        #pragma unroll
        for (int j=0;j<16;j++){ Thi[(col+j)*TSTRIDE + row] = hi[j]; Tlo[(col+j)*TSTRIDE + row] = lo[j]; }
    }
    sbias[tid] = bias[tid];
    __syncthreads();

    float hnew[4][4];

    #pragma unroll 1
    for (int step=0; step<4; ++step){
        // ===== S1: agg = M @ H   (MhiHhi + MloHhi + MhiHlo)
        f32x4 acc[4];
        #pragma unroll
        for(int m=0;m<4;m++) acc[m] = (f32x4){0,0,0,0};
        #pragma unroll
        for (int kb=0;kb<2;kb++){                 // K = 64 nodes
            bf16x8 bh = frag64(Thi, C0+r16, kb, g);
            bf16x8 bl = frag64(Tlo, C0+r16, kb, g);
            #pragma unroll
            for(int m=0;m<4;m++){
                bf16x8 ah = frag64(Mhi, m*16+r16, kb, g);
                bf16x8 al = frag64(Mlo, m*16+r16, kb, g);
                acc[m] = MFMA(ah, bh, acc[m]);
                acc[m] = MFMA(al, bh, acc[m]);
                acc[m] = MFMA(ah, bl, acc[m]);
            }
        }
        #pragma unroll
        for(int m=0;m<4;m++)
        #pragma unroll
        for(int r=0;r<4;r++){
            int row = m*16 + g*4 + r, col = C0 + r16;
            float x = acc[m][r];
            uint16_t h_ = f2b(x);
            Ahi[SW(row,col)] = h_;
            Alo[SW(row,col)] = f2b(x - b2f(h_));
        }
        __syncthreads();

        // ===== S2: neigh = agg @ Wp^T + 64*bp
        #pragma unroll
        for(int m=0;m<4;m++) acc[m] = (f32x4){0,0,0,0};
        #pragma unroll
        for (int kb=0;kb<4;kb++){
            bf16x8 wh = WFRAG(whi, 0, kb);
            bf16x8 wl = WFRAG(wlo, 0, kb);
            #pragma unroll
            for(int m=0;m<4;m++){
                bf16x8 ah = frag128(Ahi, m*16+r16, kb, g);
                bf16x8 al = frag128(Alo, m*16+r16, kb, g);
                acc[m] = MFMA(ah, wh, acc[m]);
                acc[m] = MFMA(al, wh, acc[m]);
                acc[m] = MFMA(ah, wl, acc[m]);
            }
        }
        {
            float bp = sbias[C0 + r16];
            #pragma unroll
            for(int m=0;m<4;m++)
            #pragma unroll
            for(int r=0;r<4;r++){
                int row = m*16 + g*4 + r, col = C0 + r16;
                float x = acc[m][r] + bp;
                uint16_t h_ = f2b(x);
                Nhi[SW(row,col)] = h_;
                Nlo[SW(row,col)] = f2b(x - b2f(h_));
            }
        }
        __syncthreads();

        // ===== S3: z = sig(N@Wz + H@Uz + bz); r = sig(N@Wr + H@Ur + br); hac = N@Wh
        f32x4 zac[4], rac[4], hac[4];
        #pragma unroll
        for(int m=0;m<4;m++){ zac[m]=(f32x4){0,0,0,0}; rac[m]=(f32x4){0,0,0,0}; hac[m]=(f32x4){0,0,0,0}; }
        #pragma unroll
        for (int kb=0;kb<4;kb++){
            bf16x8 wzh = WFRAG(whi,1,kb), wzl = WFRAG(wlo,1,kb);
            bf16x8 wrh = WFRAG(whi,2,kb), wrl = WFRAG(wlo,2,kb);
            bf16x8 whh = WFRAG(whi,3,kb), whl = WFRAG(wlo,3,kb);
            bf16x8 uzh = WFRAG(whi,4,kb), uzl = WFRAG(wlo,4,kb);
            bf16x8 urh = WFRAG(whi,5,kb), url = WFRAG(wlo,5,kb);
            #pragma unroll
            for(int m=0;m<4;m++){
                bf16x8 nh = frag128(Nhi, m*16+r16, kb, g);
                bf16x8 nl = frag128(Nlo, m*16+r16, kb, g);
                bf16x8 hh = frag128(Hhi, m*16+r16, kb, g);
                bf16x8 hl = frag128(Hlo, m*16+r16, kb, g);
                zac[m] = MFMA(nh, wzh, zac[m]);
                zac[m] = MFMA(nl, wzh, zac[m]);
                zac[m] = MFMA(nh, wzl, zac[m]);
                zac[m] = MFMA(hh, uzh, zac[m]);
                zac[m] = MFMA(hl, uzh, zac[m]);
                zac[m] = MFMA(hh, uzl, zac[m]);
                rac[m] = MFMA(nh, wrh, rac[m]);
                rac[m] = MFMA(nl, wrh, rac[m]);
                rac[m] = MFMA(nh, wrl, rac[m]);
                rac[m] = MFMA(hh, urh, rac[m]);
                rac[m] = MFMA(hl, urh, rac[m]);
                rac[m] = MFMA(hh, url, rac[m]);
                hac[m] = MFMA(nh, whh, hac[m]);
                hac[m] = MFMA(nl, whh, hac[m]);
                hac[m] = MFMA(nh, whl, hac[m]);
            }
        }
        float zkeep[4][4], holdv[4][4];
        {
            float bz = sbias[128 + C0 + r16];
            float br = sbias[256 + C0 + r16];
            #pragma unroll
            for(int m=0;m<4;m++)
            #pragma unroll
            for(int r=0;r<4;r++){
                int row = m*16 + g*4 + r, col = C0 + r16;
                float zz = sigm(zac[m][r] + bz);
                float rr = sigm(rac[m][r] + br);
                float hcur = b2f(Hhi[SW(row,col)]) + b2f(Hlo[SW(row,col)]);
                float uu = rr * hcur;
                uint16_t h_ = f2b(uu);
                Ahi[SW(row,col)] = h_;                 // reuse agg buffer for u = r*h
                Alo[SW(row,col)] = f2b(uu - b2f(h_));
                zkeep[m][r] = zz;
                holdv[m][r] = hcur;
            }
        }
        __syncthreads();

        // ===== S4: hac += u @ Uh^T ; ĥ = tanh(hac + bh); h' = h + z(ĥ-h)
        #pragma unroll
        for (int kb=0;kb<4;kb++){
            bf16x8 wh = WFRAG(whi, 6, kb);
            bf16x8 wl = WFRAG(wlo, 6, kb);
            #pragma unroll
            for(int m=0;m<4;m++){
                bf16x8 ah = frag128(Ahi, m*16+r16, kb, g);
                bf16x8 al = frag128(Alo, m*16+r16, kb, g);
                hac[m] = MFMA(ah, wh, hac[m]);
                hac[m] = MFMA(al, wh, hac[m]);
                hac[m] = MFMA(ah, wl, hac[m]);
            }
        }
        {
            float bh = sbias[384 + C0 + r16];
            #pragma unroll
            for(int m=0;m<4;m++){
                uint16_t hi4[4], lo4[4];
                #pragma unroll
                for(int r=0;r<4;r++){
                    float hv = tanhfast(hac[m][r] + bh);
                    float ho = holdv[m][r];
                    float hn = ho + zkeep[m][r]*(hv - ho);
                    hnew[m][r] = hn;
                    uint16_t hb16 = f2b(hn);
                    hi4[r] = hb16;
                    lo4[r] = f2b(hn - b2f(hb16));
                }
                if (step < 3){
                    int col = C0 + r16;
                    #pragma unroll
                    for(int r=0;r<4;r++){
                        int row = m*16 + g*4 + r;
                        Hhi[SW(row,col)] = hi4[r];
                        Hlo[SW(row,col)] = lo4[r];
                    }
                    int rowb = m*16 + g*4;            // transposed copy, 4 nodes packed
                    uint2 phi, plo;
                    phi.x = (uint32_t)hi4[0] | ((uint32_t)hi4[1]<<16);
                    phi.y = (uint32_t)hi4[2] | ((uint32_t)hi4[3]<<16);
                    plo.x = (uint32_t)lo4[0] | ((uint32_t)lo4[1]<<16);
                    plo.y = (uint32_t)lo4[2] | ((uint32_t)lo4[3]<<16);
                    *(uint2*)&Thi[col*TSTRIDE + rowb] = phi;
                    *(uint2*)&Tlo[col*TSTRIDE + rowb] = plo;
                }
            }
        }
        __syncthreads();
    }

    // ---- write h (f32) to output
    float* ob = out + (size_t)b*8192;
    #pragma unroll
    for(int m=0;m<4;m++)
    #pragma unroll
    for(int r=0;r<4;r++){
        int row = m*16 + g*4 + r, col = C0 + r16;
        ob[row*128 + col] = hnew[m][r];
    }
}

extern "C" void kernel_launch(void* const* d_in, const int* in_sizes, int n_in,
                              void* d_out, int out_size, void* d_ws, size_t ws_size,
                              hipStream_t stream)
{
    const float* h0   = (const float*)d_in[0];
    const float* mask = (const float*)d_in[1];
    const float* Wp   = (const float*)d_in[2];  const float* Wp_b = (const float*)d_in[3];
    const float* Wz   = (const float*)d_in[4];  const float* Wz_b = (const float*)d_in[5];
    const float* Uz   = (const float*)d_in[6];  const float* Uz_b = (const float*)d_in[7];
    const float* Wr   = (const float*)d_in[8];  const float* Wr_b = (const float*)d_in[9];
    const float* Ur   = (const float*)d_in[10]; const float* Ur_b = (const float*)d_in[11];
    const float* Wh   = (const float*)d_in[12]; const float* Wh_b = (const float*)d_in[13];
    const float* Uh   = (const float*)d_in[14]; const float* Uh_b = (const float*)d_in[15];

    uint16_t* whi = (uint16_t*)d_ws;                                   // 7*16384 bf16
    uint16_t* wlo = whi + 7*16384;                                     // 7*16384 bf16
    float*    bias = (float*)((char*)d_ws + 2*7*16384*sizeof(uint16_t)); // 512 f32

    prep_weights<<<448, 256, 0, stream>>>(Wp, Wz, Wr, Wh, Uz, Ur, Uh,
                                          Wp_b, Wz_b, Uz_b, Wr_b, Ur_b, Wh_b, Uh_b,
                                          whi, wlo, bias);
    ggsnn<<<4096, 512, 0, stream>>>(h0, mask, whi, wlo, bias, (float*)d_out);
}